// Round 6
// baseline (263.871 us; speedup 1.0000x reference)
//
#include <hip/hip_runtime.h>

// JointLoss on MI355X. N=8192, D=256. Output: 1 fp32 scalar.
//
// ws layout (bytes):
//   [0,      32768)   rank[N] int (atomic-accumulated permutation 0..N-1)
//   [32768,  65536)   at_risk[N] float
//   [65536,  66560)   slots: 64 x 4 quantities (cox, cnt, sim, contrast)
//   [66560,  328704)  gsum[2][8192][4] float (per matrix,row,group exp-sums)
//   [393216, +2M)     packed wsi fp8 e4m3, k-step-major pk[ks][row][32B] (ks=k/32)
//   [393216+2M, +4M)  packed omic fp8
//
// R1: same-address atomics serialize -> slot-spread.
// R2: 64-row blocks streamed 1 GB of B from LLC -> latency-bound 100us.
// R3: 128-VGPR A-residency -> 2 waves/SIMD, barrier-coupled; 72us.
// R5: occupancy fixed (4 w/SIMD) but LDS-BW (8 MB/CU) + exp-VALU bound: 67us.
//     Now fp8: half B bytes AND 64 rows/wave in 64 VGPRs -> LDS 2 MB/CU,
//     same MFMA rate (non-scaled fp8 = bf16 rate). Quant err ~1e-4 on scalar.

#define NN 8192
#define DD 256
#define NSLOT 64

typedef __attribute__((ext_vector_type(4))) float f32x4;

__device__ inline void gl_lds16(const void* g, void* l) {
  // async 16B/lane global->LDS; LDS dst is wave-uniform base + lane*16
  __builtin_amdgcn_global_load_lds(
      (const __attribute__((address_space(1))) unsigned int*)g,
      (__attribute__((address_space(3))) unsigned int*)l, 16, 0, 0);
}

// ---------------------------------------------------------------------------
// K1: O(N^2) brute-force rank + at-risk sums (replaces sort+cumsum).
//   rank_i    = #{j : t_j < t_i or (t_j==t_i and j<i)}
//   at_risk_i = sum over complement (incl. self) of exp(clip(lr_j,-10,10))
// grid (32 i-blocks, 16 j-chunks) x 256 thr -> 2 blocks/CU.
// ---------------------------------------------------------------------------
__global__ void __launch_bounds__(256) k_rank_atrisk(
    const float* __restrict__ times, const float* __restrict__ lr,
    int* __restrict__ rank, float* __restrict__ at_risk) {
  __shared__ __align__(16) float st[512];
  __shared__ __align__(16) float se[512];
  const int tid = threadIdx.x;
  const int i = blockIdx.x * 256 + tid;
  const int jbase = blockIdx.y * 512;
  for (int p = tid; p < 512; p += 256) {
    float t = times[jbase + p];
    float l = lr[jbase + p];
    l = fminf(fmaxf(l, -10.f), 10.f);
    st[p] = t;
    se[p] = __expf(l);
  }
  __syncthreads();
  const float ti = times[i];
  int rk = 0;
  float ar = 0.f;
  for (int p4 = 0; p4 < 512; p4 += 4) {
    float4 tv = *(const float4*)&st[p4];
    float4 ev = *(const float4*)&se[p4];
    const int j0 = jbase + p4;
#define K1_STEP(c, jo)                                              \
    {                                                               \
      bool c1 = (c < ti) || ((c == ti) && ((j0 + jo) < i));         \
      rk += c1 ? 1 : 0;                                             \
      ar += c1 ? 0.f : ((jo == 0) ? ev.x : (jo == 1) ? ev.y         \
                         : (jo == 2) ? ev.z : ev.w);                \
    }
    K1_STEP(tv.x, 0) K1_STEP(tv.y, 1) K1_STEP(tv.z, 2) K1_STEP(tv.w, 3)
#undef K1_STEP
  }
  atomicAdd(&rank[i], rk);
  atomicAdd(&at_risk[i], ar);
}

// ---------------------------------------------------------------------------
// K2: per-row (one wave per row): norms, cos-sim, Cox li, normalize -> fp8
// -> scatter into rank-permuted packed layout. Block-reduce + slot atomics.
// ---------------------------------------------------------------------------
__global__ void __launch_bounds__(256) k_rows(
    const float* __restrict__ lr, const int* __restrict__ censor,
    const float* __restrict__ wsi, const float* __restrict__ omic,
    const int* __restrict__ rank, const float* __restrict__ at_risk,
    unsigned char* __restrict__ pw, unsigned char* __restrict__ po,
    float* __restrict__ slots) {
  __shared__ float red[4][3];
  const int tid = threadIdx.x;
  const int lane = tid & 63;
  const int wv = tid >> 6;
  const int i = blockIdx.x * 4 + wv;
  const float4 w = ((const float4*)(wsi + (size_t)i * DD))[lane];
  const float4 o = ((const float4*)(omic + (size_t)i * DD))[lane];
  float nw = w.x * w.x + w.y * w.y + w.z * w.z + w.w * w.w;
  float no = o.x * o.x + o.y * o.y + o.z * o.z + o.w * o.w;
  float dd = w.x * o.x + w.y * o.y + w.z * o.z + w.w * o.w;
  for (int m = 1; m < 64; m <<= 1) {
    nw += __shfl_xor(nw, m);
    no += __shfl_xor(no, m);
    dd += __shfl_xor(dd, m);
  }
  const float nws = sqrtf(nw), nos = sqrtf(no);
  if (lane == 0) {
    float c = dd / (fmaxf(nws, 1e-8f) * fmaxf(nos, 1e-8f));
    c = fminf(fmaxf(c, -1.f), 1.f);
    float l = fminf(fmaxf(lr[i], -10.f), 10.f);
    float li = l - logf(at_risk[i] + 1e-15f);
    bool cen = (censor[i] == 1);
    red[wv][0] = cen ? li : 0.f;
    red[wv][1] = cen ? 1.f : 0.f;
    red[wv][2] = 1.f - c;
  }
  const int r = rank[i]; // permuted row; rank>>11 == risk group
  const float iw = 1.f / fmaxf(nws, 1e-12f);
  const float io = 1.f / fmaxf(nos, 1e-12f);
  // pack 4 normalized values -> 4 fp8 e4m3 bytes
  int zw = __builtin_amdgcn_cvt_pk_fp8_f32(w.x * iw, w.y * iw, 0, false);
  zw = __builtin_amdgcn_cvt_pk_fp8_f32(w.z * iw, w.w * iw, zw, true);
  int zo = __builtin_amdgcn_cvt_pk_fp8_f32(o.x * io, o.y * io, 0, false);
  zo = __builtin_amdgcn_cvt_pk_fp8_f32(o.z * io, o.w * io, zo, true);
  // lane covers k = lane*4.. -> ks = lane>>3, byte offset (lane&7)*4 in 32B chunk
  const size_t off = ((size_t)(lane >> 3) * NN + r) * 32 + (lane & 7) * 4;
  *(unsigned int*)(pw + off) = (unsigned int)zw;
  *(unsigned int*)(po + off) = (unsigned int)zo;
  __syncthreads();
  if (tid < 3) {
    float v = red[0][tid] + red[1][tid] + red[2][tid] + red[3][tid];
    atomicAdd(&slots[tid * NSLOT + (blockIdx.x & (NSLOT - 1))], v);
  }
}

// ---------------------------------------------------------------------------
// K3: contrastive exp-sums, fp8. grid (16 cb, 16 rb, 2 mz) x 512 thr,
// 2 blocks/CU (4 waves/SIMD). Block = 512 rows x 512 cols (8 stages x 64).
// Wave owns 64 rows: afrag[4][8] longs = 64 VGPR register-resident.
// B staged via global_load_lds into double-buffered LDS (2 x 16 KB).
//
// LDS: 16B unit(ks,h,c) = (ks*2+h)*64 + c holds B[col=c][k=ks*32+h*16..+15].
// DMA: wave wv (=ks), issue p (=h), lane (=c): src = pk[(wv*NN+col)*32+p*16].
// Frag read (ct,ks) lane(q,lo): ds_read_b64 at ks*2048 + ct*256
//   + (q>>1)*1024 + lo*16 + (q&1)*8  (lane-linear, conflict-light).
// Group constant per block: g = cb>>2 (512 cols inside one 2048-col group).
// ---------------------------------------------------------------------------
__global__ void __launch_bounds__(512, 4) k_contrast(
    const unsigned char* __restrict__ pw, const unsigned char* __restrict__ po,
    float* __restrict__ gsum) {
  __shared__ __align__(16) unsigned char sbuf[2][16384]; // 2 x 16 KB
  const int tid = threadIdx.x;
  const int lane = tid & 63;
  const int wv = tid >> 6;                 // 0..7 (= ks this wave stages)
  const int lo = lane & 15, q = lane >> 4; // MFMA frag coords
  const int cb = blockIdx.x, rb = blockIdx.y, mz = blockIdx.z;
  const unsigned char* __restrict__ pk = (mz == 0) ? pw : po;
  const int rowbase = rb * 512 + wv * 64;
  const int colstart = cb * 512;
  const int g = cb >> 2;

  // A fragments: 4 row-tiles x 8 k-steps, 2 VGPR each = 64 VGPRs resident
  long afrag[4][8];
#pragma unroll
  for (int rt = 0; rt < 4; ++rt) {
    const size_t row = rowbase + rt * 16 + lo;
#pragma unroll
    for (int ks = 0; ks < 8; ++ks)
      afrag[rt][ks] = *(const long*)(pk + ((size_t)ks * NN + row) * 32 + q * 8);
  }

  // DMA stage 0
  const unsigned char* gsrc = pk + ((size_t)wv * NN + colstart + lane) * 32;
  gl_lds16(gsrc, &sbuf[0][(wv * 2 + 0) * 1024]);
  gl_lds16(gsrc + 16, &sbuf[0][(wv * 2 + 1) * 1024]);
  __syncthreads();

  float s[4][4] = {{0.f}};
  const int lbase = (q >> 1) * 1024 + lo * 16 + (q & 1) * 8; // per-lane const

#pragma unroll 1
  for (int st = 0; st < 8; ++st) {
    // async-prefetch next stage into other buffer (drained at barrier)
    if (st < 7) {
      const unsigned char* gs = gsrc + (size_t)(st + 1) * 64 * 32;
      unsigned char* lb = &sbuf[(st + 1) & 1][0];
      gl_lds16(gs, lb + (wv * 2 + 0) * 1024);
      gl_lds16(gs + 16, lb + (wv * 2 + 1) * 1024);
    }
    const unsigned char* buf = &sbuf[st & 1][0];
    const bool diagw = (rowbase == colstart + st * 64);
#pragma unroll
    for (int ct = 0; ct < 4; ++ct) {
      f32x4 acc[4];
#pragma unroll
      for (int rt = 0; rt < 4; ++rt) { f32x4 z = {0.f, 0.f, 0.f, 0.f}; acc[rt] = z; }
      long bf[4];
#pragma unroll
      for (int ks = 0; ks < 4; ++ks)
        bf[ks] = *(const long*)&buf[ks * 2048 + ct * 256 + lbase];
#pragma unroll
      for (int ks = 0; ks < 4; ++ks)
#pragma unroll
        for (int rt = 0; rt < 4; ++rt)
          acc[rt] = __builtin_amdgcn_mfma_f32_16x16x32_fp8_fp8(afrag[rt][ks], bf[ks], acc[rt], 0, 0, 0);
#pragma unroll
      for (int ks = 0; ks < 4; ++ks)
        bf[ks] = *(const long*)&buf[(ks + 4) * 2048 + ct * 256 + lbase];
#pragma unroll
      for (int ks = 0; ks < 4; ++ks)
#pragma unroll
        for (int rt = 0; rt < 4; ++rt)
          acc[rt] = __builtin_amdgcn_mfma_f32_16x16x32_fp8_fp8(afrag[rt][ks + 4], bf[ks], acc[rt], 0, 0, 0);
      // epilogue: exp(sim-10), sim = dot/0.1 (unit vectors => sim<=10)
#pragma unroll
      for (int rt = 0; rt < 4; ++rt)
#pragma unroll
        for (int r = 0; r < 4; ++r) {
          float e = __expf(fmaf(acc[rt][r], 10.f, -10.f));
          // exact diagonal exclusion: row rt*16+q*4+r == col ct*16+lo
          if (diagw && rt == ct && lo == q * 4 + r) e = 0.f;
          s[rt][r] += e;
        }
    }
    __syncthreads();
  }

  // flush: reduce over 16 col-lanes, one atomic per (row, group)
#pragma unroll
  for (int rt = 0; rt < 4; ++rt)
#pragma unroll
    for (int r = 0; r < 4; ++r) {
      float v = s[rt][r];
      v += __shfl_xor(v, 1); v += __shfl_xor(v, 2);
      v += __shfl_xor(v, 4); v += __shfl_xor(v, 8);
      if (lo == 0) {
        const int row = rowbase + rt * 16 + q * 4 + r; // C/D: row=(lane>>4)*4+reg
        atomicAdd(&gsum[((size_t)mz * NN + row) * 4 + g], v);
      }
    }
}

// ---------------------------------------------------------------------------
// K3b: per-row LSE difference + reduce. loss = log(sum_all) - log(sum_pos).
// ---------------------------------------------------------------------------
__global__ void __launch_bounds__(256) k_lse(
    const float* __restrict__ gsum, float* __restrict__ slots) {
  __shared__ float r4[4];
  const int tid = threadIdx.x;
  const int lane = tid & 63, wv = tid >> 6;
  const int idx = blockIdx.x * 256 + tid; // (matrix, row) flattened
  const float4 v = ((const float4*)gsum)[idx];
  const int row = idx & (NN - 1);
  const int gg = row >> 11; // group of permuted row
  const float sg = (gg == 0) ? v.x : (gg == 1) ? v.y : (gg == 2) ? v.z : v.w;
  float loss = logf(v.x + v.y + v.z + v.w) - logf(sg);
  for (int m = 1; m < 64; m <<= 1) loss += __shfl_xor(loss, m);
  if (lane == 0) r4[wv] = loss;
  __syncthreads();
  if (tid == 0)
    atomicAdd(&slots[3 * NSLOT + (blockIdx.x & (NSLOT - 1))],
              r4[0] + r4[1] + r4[2] + r4[3]);
}

// ---------------------------------------------------------------------------
// K4: reduce slots, combine scalar.
// ---------------------------------------------------------------------------
__global__ void k_final(const float* __restrict__ slots, float* __restrict__ out) {
  const int lane = threadIdx.x & 63;
  float cox_s = (lane < NSLOT) ? slots[0 * NSLOT + lane] : 0.f;
  float cnt_s = (lane < NSLOT) ? slots[1 * NSLOT + lane] : 0.f;
  float sim_s = (lane < NSLOT) ? slots[2 * NSLOT + lane] : 0.f;
  float con_s = (lane < NSLOT) ? slots[3 * NSLOT + lane] : 0.f;
  for (int m = 1; m < 64; m <<= 1) {
    cox_s += __shfl_xor(cox_s, m);
    cnt_s += __shfl_xor(cnt_s, m);
    sim_s += __shfl_xor(sim_s, m);
    con_s += __shfl_xor(con_s, m);
  }
  if (lane == 0) {
    float cnt = fmaxf(cnt_s, 1.f);
    float cox = -cox_s / cnt;
    float sim = sim_s / (float)NN;
    float contrast = 0.1f * 0.5f * con_s / (float)NN;
    out[0] = cox + sim + contrast;
  }
}

extern "C" void kernel_launch(void* const* d_in, const int* in_sizes, int n_in,
                              void* d_out, int out_size, void* d_ws, size_t ws_size,
                              hipStream_t stream) {
  const float* lr = (const float*)d_in[0];
  const float* times = (const float*)d_in[1];
  const int* censor = (const int*)d_in[2];
  const float* wsi = (const float*)d_in[3];
  const float* omic = (const float*)d_in[4];
  float* out = (float*)d_out;

  char* ws = (char*)d_ws;
  int* rank = (int*)ws;
  float* at_risk = (float*)(ws + 32768);
  float* slots = (float*)(ws + 65536);
  float* gsum = (float*)(ws + 66560);
  unsigned char* pw = (unsigned char*)(ws + 393216);
  unsigned char* po = (unsigned char*)(ws + 393216 + 2097152);

  // one memset covers rank, at_risk, slots, gsum
  (void)hipMemsetAsync(d_ws, 0, 328704, stream);
  k_rank_atrisk<<<dim3(32, 16), 256, 0, stream>>>(times, lr, rank, at_risk);
  k_rows<<<2048, 256, 0, stream>>>(lr, censor, wsi, omic, rank, at_risk, pw, po, slots);
  k_contrast<<<dim3(16, 16, 2), 512, 0, stream>>>(pw, po, gsum);
  k_lse<<<64, 256, 0, stream>>>(gsum, slots);
  k_final<<<1, 64, 0, stream>>>(slots, out);
}

// Round 7
// 218.380 us; speedup vs baseline: 1.2083x; 1.2083x over previous
//
#include <hip/hip_runtime.h>

// JointLoss on MI355X. N=8192, D=256. Output: 1 fp32 scalar.
//
// ws layout (bytes):
//   [0,      32768)   rank[N] int (atomic-accumulated permutation 0..N-1)
//   [32768,  65536)   at_risk[N] float
//   [65536,  66560)   slots: 64 x 4 quantities (cox, cnt, sim, contrast)
//   [66560,  328704)  gsum[2][8192][4] float (per matrix,row,group exp-sums)
//   [393216, +2M)     packed wsi fp8 e4m3: byte ((kp*4+q)*N + row)*16 + h*8 + j
//                     holds emb[row][k], k = (2kp+h)*32 + q*8 + j
//   [393216+2M, +4M)  packed omic fp8 (same layout)
//
// R1: same-address atomics serialize -> slot-spread.
// R2: 64-row blocks streamed 1 GB of B from LLC -> latency-bound 100us.
// R3: 128-VGPR A-residency -> 2 waves/SIMD barrier-coupled; 72us.
// R5: LDS-BW (8 MB/CU) + exp-VALU bound at 67us -> motivated fp8.
// R6: scalar-i64 frag arrays spilled to scratch (305+179 MB HBM, 154us) and
//     strided ds_read_b64 hit 4M bank conflicts. Now: ext-vector i32x4 frags
//     (AGPR-allocatable, bit_cast to i64 pairs at MFMA), frag-pair-linear LDS
//     (ds_read_b128, m97 pattern), DMA-order-matched global layout.

#define NN 8192
#define DD 256
#define NSLOT 64

typedef __attribute__((ext_vector_type(4))) float f32x4;
typedef __attribute__((ext_vector_type(4))) int i32x4;
typedef __attribute__((ext_vector_type(2))) long l64x2;

__device__ inline void gl_lds16(const void* g, void* l) {
  // async 16B/lane global->LDS; LDS dst must be wave-uniform base + lane*16
  __builtin_amdgcn_global_load_lds(
      (const __attribute__((address_space(1))) unsigned int*)g,
      (__attribute__((address_space(3))) unsigned int*)l, 16, 0, 0);
}

// ---------------------------------------------------------------------------
// K1: O(N^2) brute-force rank + at-risk sums (replaces sort+cumsum).
//   rank_i    = #{j : t_j < t_i or (t_j==t_i and j<i)}
//   at_risk_i = sum over complement (incl. self) of exp(clip(lr_j,-10,10))
// grid (32 i-blocks, 16 j-chunks) x 256 thr.
// ---------------------------------------------------------------------------
__global__ void __launch_bounds__(256) k_rank_atrisk(
    const float* __restrict__ times, const float* __restrict__ lr,
    int* __restrict__ rank, float* __restrict__ at_risk) {
  __shared__ __align__(16) float st[512];
  __shared__ __align__(16) float se[512];
  const int tid = threadIdx.x;
  const int i = blockIdx.x * 256 + tid;
  const int jbase = blockIdx.y * 512;
  for (int p = tid; p < 512; p += 256) {
    float t = times[jbase + p];
    float l = lr[jbase + p];
    l = fminf(fmaxf(l, -10.f), 10.f);
    st[p] = t;
    se[p] = __expf(l);
  }
  __syncthreads();
  const float ti = times[i];
  int rk = 0;
  float ar = 0.f;
  for (int p4 = 0; p4 < 512; p4 += 4) {
    float4 tv = *(const float4*)&st[p4];
    float4 ev = *(const float4*)&se[p4];
    const int j0 = jbase + p4;
#define K1_STEP(c, jo)                                              \
    {                                                               \
      bool c1 = (c < ti) || ((c == ti) && ((j0 + jo) < i));         \
      rk += c1 ? 1 : 0;                                             \
      ar += c1 ? 0.f : ((jo == 0) ? ev.x : (jo == 1) ? ev.y         \
                         : (jo == 2) ? ev.z : ev.w);                \
    }
    K1_STEP(tv.x, 0) K1_STEP(tv.y, 1) K1_STEP(tv.z, 2) K1_STEP(tv.w, 3)
#undef K1_STEP
  }
  atomicAdd(&rank[i], rk);
  atomicAdd(&at_risk[i], ar);
}

// ---------------------------------------------------------------------------
// K2: per-row (one wave per row): norms, cos-sim, Cox li, normalize -> fp8
// -> scatter into rank-permuted packed layout. Block-reduce + slot atomics.
// Lane covers k = lane*4..+3: kp=lane>>4, h=(lane>>3)&1, q=(lane>>1)&3,
// j0=(lane&1)*4 -> offset ((kp*4+q)*NN + r)*16 + h*8 + j0.
// ---------------------------------------------------------------------------
__global__ void __launch_bounds__(256) k_rows(
    const float* __restrict__ lr, const int* __restrict__ censor,
    const float* __restrict__ wsi, const float* __restrict__ omic,
    const int* __restrict__ rank, const float* __restrict__ at_risk,
    unsigned char* __restrict__ pw, unsigned char* __restrict__ po,
    float* __restrict__ slots) {
  __shared__ float red[4][3];
  const int tid = threadIdx.x;
  const int lane = tid & 63;
  const int wv = tid >> 6;
  const int i = blockIdx.x * 4 + wv;
  const float4 w = ((const float4*)(wsi + (size_t)i * DD))[lane];
  const float4 o = ((const float4*)(omic + (size_t)i * DD))[lane];
  float nw = w.x * w.x + w.y * w.y + w.z * w.z + w.w * w.w;
  float no = o.x * o.x + o.y * o.y + o.z * o.z + o.w * o.w;
  float dd = w.x * o.x + w.y * o.y + w.z * o.z + w.w * o.w;
  for (int m = 1; m < 64; m <<= 1) {
    nw += __shfl_xor(nw, m);
    no += __shfl_xor(no, m);
    dd += __shfl_xor(dd, m);
  }
  const float nws = sqrtf(nw), nos = sqrtf(no);
  if (lane == 0) {
    float c = dd / (fmaxf(nws, 1e-8f) * fmaxf(nos, 1e-8f));
    c = fminf(fmaxf(c, -1.f), 1.f);
    float l = fminf(fmaxf(lr[i], -10.f), 10.f);
    float li = l - logf(at_risk[i] + 1e-15f);
    bool cen = (censor[i] == 1);
    red[wv][0] = cen ? li : 0.f;
    red[wv][1] = cen ? 1.f : 0.f;
    red[wv][2] = 1.f - c;
  }
  const int r = rank[i]; // permuted row; rank>>11 == risk group
  const float iw = 1.f / fmaxf(nws, 1e-12f);
  const float io = 1.f / fmaxf(nos, 1e-12f);
  int zw = __builtin_amdgcn_cvt_pk_fp8_f32(w.x * iw, w.y * iw, 0, false);
  zw = __builtin_amdgcn_cvt_pk_fp8_f32(w.z * iw, w.w * iw, zw, true);
  int zo = __builtin_amdgcn_cvt_pk_fp8_f32(o.x * io, o.y * io, 0, false);
  zo = __builtin_amdgcn_cvt_pk_fp8_f32(o.z * io, o.w * io, zo, true);
  const size_t off = ((size_t)((lane >> 4) * 4 + ((lane >> 1) & 3)) * NN + r) * 16
                     + ((lane >> 3) & 1) * 8 + (lane & 1) * 4;
  *(unsigned int*)(pw + off) = (unsigned int)zw;
  *(unsigned int*)(po + off) = (unsigned int)zo;
  __syncthreads();
  if (tid < 3) {
    float v = red[0][tid] + red[1][tid] + red[2][tid] + red[3][tid];
    atomicAdd(&slots[tid * NSLOT + (blockIdx.x & (NSLOT - 1))], v);
  }
}

// ---------------------------------------------------------------------------
// K3: contrastive exp-sums, fp8. grid (16 cb, 16 rb, 2 mz) x 512 thr,
// 2 blocks/CU. Block = 512 rows x 512 cols (8 stages x 64 cols).
// Wave owns 64 rows: afrag[4][4] i32x4 = 64 VGPRs (ext-vector: AGPR-able).
// B double-buffered LDS 2 x 16 KB via global_load_lds.
//
// LDS stage layout: pairbase(ct,kp) = (ct*4+kp)*1024; lane l holds 16 B =
// frag(2kp) 8B || frag(2kp+1) 8B at pairbase + l*16 -> ds_read_b128
// lane-linear (m97 pattern, conflict-free).
// DMA chunk u=(wv*2+p)*64+lane: byte u*16 -> fi2=u>>6 (=ct*4+kp), l=u&63,
// q=l>>4, lo=l&15, src = pk + ((kp*4+q)*NN + col)*16 (16 B = h=0,1 octets,
// one col) -> lands exactly frag-pair-linear. LDS dst = (wv*2+p)*1024+lane*16.
// Group constant per block: g = cb>>2.
// ---------------------------------------------------------------------------
__global__ void __launch_bounds__(512, 4) k_contrast(
    const unsigned char* __restrict__ pw, const unsigned char* __restrict__ po,
    float* __restrict__ gsum) {
  __shared__ __align__(16) unsigned char sbuf[2][16384]; // 2 x 16 KB
  const int tid = threadIdx.x;
  const int lane = tid & 63;
  const int wv = tid >> 6;                 // 0..7
  const int lo = lane & 15, q = lane >> 4; // MFMA frag coords
  const int cb = blockIdx.x, rb = blockIdx.y, mz = blockIdx.z;
  const unsigned char* __restrict__ pk = (mz == 0) ? pw : po;
  const int rowbase = rb * 512 + wv * 64;
  const int colstart = cb * 512;
  const int g = cb >> 2;

  // A fragments: 4 row-tiles x 4 kp-pairs x 16 B = 64 VGPRs, resident
  i32x4 afrag[4][4];
#pragma unroll
  for (int rt = 0; rt < 4; ++rt) {
    const size_t row = rowbase + rt * 16 + lo;
#pragma unroll
    for (int kp = 0; kp < 4; ++kp)
      afrag[rt][kp] = *(const i32x4*)(pk + ((size_t)(kp * 4 + q) * NN + row) * 16);
  }

  // per-lane DMA source (advances +1024 B per stage = +64 cols)
  const int u = wv * 128 + lane; // chunk p=0; p=1 is u+64
  const int u1 = u + 64;
  const unsigned char* gsrc0 = pk +
      ((size_t)(((u >> 6) & 3) * 4 + ((u >> 4) & 3)) * NN
       + colstart + (u >> 8) * 16 + (u & 15)) * 16;
  const unsigned char* gsrc1 = pk +
      ((size_t)(((u1 >> 6) & 3) * 4 + ((u1 >> 4) & 3)) * NN
       + colstart + (u1 >> 8) * 16 + (u1 & 15)) * 16;
  unsigned char* const ld0 = &sbuf[0][(wv * 2 + 0) * 1024 + 0];
  unsigned char* const ld1 = &sbuf[0][(wv * 2 + 1) * 1024 + 0];

  gl_lds16(gsrc0, ld0);
  gl_lds16(gsrc1, ld1);
  __syncthreads();

  float s[4][4] = {{0.f}};

#pragma unroll 1
  for (int st = 0; st < 8; ++st) {
    if (st < 7) { // async-prefetch next stage into other buffer
      const size_t adv = (size_t)(st + 1) * 1024;
      const size_t bofs = ((st + 1) & 1) ? 16384 : 0;
      gl_lds16(gsrc0 + adv, ld0 + bofs);
      gl_lds16(gsrc1 + adv, ld1 + bofs);
    }
    const unsigned char* buf = &sbuf[st & 1][0];
    const bool diagw = (rowbase == colstart + st * 64);
#pragma unroll
    for (int ct = 0; ct < 4; ++ct) {
      f32x4 acc[4];
#pragma unroll
      for (int rt = 0; rt < 4; ++rt) { f32x4 z = {0.f, 0.f, 0.f, 0.f}; acc[rt] = z; }
#pragma unroll
      for (int kh = 0; kh < 2; ++kh) { // kp pairs {0,1} then {2,3}
        l64x2 b0 = __builtin_bit_cast(l64x2,
            *(const i32x4*)&buf[(ct * 4 + kh * 2 + 0) * 1024 + lane * 16]);
        l64x2 b1 = __builtin_bit_cast(l64x2,
            *(const i32x4*)&buf[(ct * 4 + kh * 2 + 1) * 1024 + lane * 16]);
        l64x2 a0[4], a1[4];
#pragma unroll
        for (int rt = 0; rt < 4; ++rt) {
          a0[rt] = __builtin_bit_cast(l64x2, afrag[rt][kh * 2 + 0]);
          a1[rt] = __builtin_bit_cast(l64x2, afrag[rt][kh * 2 + 1]);
        }
#pragma unroll
        for (int rt = 0; rt < 4; ++rt)
          acc[rt] = __builtin_amdgcn_mfma_f32_16x16x32_fp8_fp8(a0[rt][0], b0[0], acc[rt], 0, 0, 0);
#pragma unroll
        for (int rt = 0; rt < 4; ++rt)
          acc[rt] = __builtin_amdgcn_mfma_f32_16x16x32_fp8_fp8(a0[rt][1], b0[1], acc[rt], 0, 0, 0);
#pragma unroll
        for (int rt = 0; rt < 4; ++rt)
          acc[rt] = __builtin_amdgcn_mfma_f32_16x16x32_fp8_fp8(a1[rt][0], b1[0], acc[rt], 0, 0, 0);
#pragma unroll
        for (int rt = 0; rt < 4; ++rt)
          acc[rt] = __builtin_amdgcn_mfma_f32_16x16x32_fp8_fp8(a1[rt][1], b1[1], acc[rt], 0, 0, 0);
      }
      // epilogue: exp(sim-10), sim = dot/0.1 (unit vectors => sim<=10)
      if (diagw) {
#pragma unroll
        for (int rt = 0; rt < 4; ++rt)
#pragma unroll
          for (int r = 0; r < 4; ++r) {
            float e = __expf(fmaf(acc[rt][r], 10.f, -10.f));
            if (rt == ct && lo == q * 4 + r) e = 0.f; // exact diagonal
            s[rt][r] += e;
          }
      } else {
#pragma unroll
        for (int rt = 0; rt < 4; ++rt)
#pragma unroll
          for (int r = 0; r < 4; ++r)
            s[rt][r] += __expf(fmaf(acc[rt][r], 10.f, -10.f));
      }
    }
    __syncthreads();
  }

  // flush: reduce over 16 col-lanes, one atomic per (row, group)
#pragma unroll
  for (int rt = 0; rt < 4; ++rt)
#pragma unroll
    for (int r = 0; r < 4; ++r) {
      float v = s[rt][r];
      v += __shfl_xor(v, 1); v += __shfl_xor(v, 2);
      v += __shfl_xor(v, 4); v += __shfl_xor(v, 8);
      if (lo == 0) {
        const int row = rowbase + rt * 16 + q * 4 + r; // C/D: row=(lane>>4)*4+reg
        atomicAdd(&gsum[((size_t)mz * NN + row) * 4 + g], v);
      }
    }
}

// ---------------------------------------------------------------------------
// K3b: per-row LSE difference + reduce. loss = log(sum_all) - log(sum_pos).
// ---------------------------------------------------------------------------
__global__ void __launch_bounds__(256) k_lse(
    const float* __restrict__ gsum, float* __restrict__ slots) {
  __shared__ float r4[4];
  const int tid = threadIdx.x;
  const int lane = tid & 63, wv = tid >> 6;
  const int idx = blockIdx.x * 256 + tid; // (matrix, row) flattened
  const float4 v = ((const float4*)gsum)[idx];
  const int row = idx & (NN - 1);
  const int gg = row >> 11; // group of permuted row
  const float sg = (gg == 0) ? v.x : (gg == 1) ? v.y : (gg == 2) ? v.z : v.w;
  float loss = logf(v.x + v.y + v.z + v.w) - logf(sg);
  for (int m = 1; m < 64; m <<= 1) loss += __shfl_xor(loss, m);
  if (lane == 0) r4[wv] = loss;
  __syncthreads();
  if (tid == 0)
    atomicAdd(&slots[3 * NSLOT + (blockIdx.x & (NSLOT - 1))],
              r4[0] + r4[1] + r4[2] + r4[3]);
}

// ---------------------------------------------------------------------------
// K4: reduce slots, combine scalar.
// ---------------------------------------------------------------------------
__global__ void k_final(const float* __restrict__ slots, float* __restrict__ out) {
  const int lane = threadIdx.x & 63;
  float cox_s = (lane < NSLOT) ? slots[0 * NSLOT + lane] : 0.f;
  float cnt_s = (lane < NSLOT) ? slots[1 * NSLOT + lane] : 0.f;
  float sim_s = (lane < NSLOT) ? slots[2 * NSLOT + lane] : 0.f;
  float con_s = (lane < NSLOT) ? slots[3 * NSLOT + lane] : 0.f;
  for (int m = 1; m < 64; m <<= 1) {
    cox_s += __shfl_xor(cox_s, m);
    cnt_s += __shfl_xor(cnt_s, m);
    sim_s += __shfl_xor(sim_s, m);
    con_s += __shfl_xor(con_s, m);
  }
  if (lane == 0) {
    float cnt = fmaxf(cnt_s, 1.f);
    float cox = -cox_s / cnt;
    float sim = sim_s / (float)NN;
    float contrast = 0.1f * 0.5f * con_s / (float)NN;
    out[0] = cox + sim + contrast;
  }
}

extern "C" void kernel_launch(void* const* d_in, const int* in_sizes, int n_in,
                              void* d_out, int out_size, void* d_ws, size_t ws_size,
                              hipStream_t stream) {
  const float* lr = (const float*)d_in[0];
  const float* times = (const float*)d_in[1];
  const int* censor = (const int*)d_in[2];
  const float* wsi = (const float*)d_in[3];
  const float* omic = (const float*)d_in[4];
  float* out = (float*)d_out;

  char* ws = (char*)d_ws;
  int* rank = (int*)ws;
  float* at_risk = (float*)(ws + 32768);
  float* slots = (float*)(ws + 65536);
  float* gsum = (float*)(ws + 66560);
  unsigned char* pw = (unsigned char*)(ws + 393216);
  unsigned char* po = (unsigned char*)(ws + 393216 + 2097152);

  // one memset covers rank, at_risk, slots, gsum
  (void)hipMemsetAsync(d_ws, 0, 328704, stream);
  k_rank_atrisk<<<dim3(32, 16), 256, 0, stream>>>(times, lr, rank, at_risk);
  k_rows<<<2048, 256, 0, stream>>>(lr, censor, wsi, omic, rank, at_risk, pw, po, slots);
  k_contrast<<<dim3(16, 16, 2), 512, 0, stream>>>(pw, po, gsum);
  k_lse<<<64, 256, 0, stream>>>(gsum, slots);
  k_final<<<1, 64, 0, stream>>>(slots, out);
}

// Round 8
// 169.695 us; speedup vs baseline: 1.5550x; 1.2869x over previous
//
#include <hip/hip_runtime.h>

// JointLoss on MI355X. N=8192, D=256. Output: 1 fp32 scalar.
//
// ws layout (bytes):
//   [0,      32768)   rank[N] int (atomic-accumulated permutation 0..N-1)
//   [32768,  65536)   at_risk[N] float
//   [65536,  66560)   slots: 64 x 4 quantities (cox, cnt, sim, contrast)
//   [66560,  328704)  gsum[2][8192][4] float (per matrix,row,group exp-sums)
//   [393216, +2M)     packed wsi fp8 e4m3: byte ((kp*4+q)*N + row)*16 + h*8 + j
//                     holds emb[row][k], k = (2kp+h)*32 + q*8 + j
//   [393216+2M, +4M)  packed omic fp8 (same layout)
//
// R1: same-address atomics serialize -> slot-spread.
// R2: 64-row blocks streamed 1 GB of B from LLC -> latency-bound 100us.
// R3: 128-VGPR A-residency -> 2 waves/SIMD barrier-coupled; 72us.
// R5: LDS-BW + exp-VALU bound at 67us -> motivated fp8.
// R6: scalar-i64 frags spilled + ds_read_b64 bank conflicts; 154us.
// R7: conflicts 0 but still spill-bound: launch_bounds(512,4) = 128-reg
//     unified budget vs ~130 needed -> per-stage spill (175 MB WRITE).
//     Now: 256-thr blocks, launch_bounds(256,3) -> 168-reg budget, 3 blk/CU.

#define NN 8192
#define DD 256
#define NSLOT 64

typedef __attribute__((ext_vector_type(4))) float f32x4;
typedef __attribute__((ext_vector_type(4))) int i32x4;
typedef __attribute__((ext_vector_type(2))) long l64x2;

__device__ inline void gl_lds16(const void* g, void* l) {
  // async 16B/lane global->LDS; LDS dst must be wave-uniform base + lane*16
  __builtin_amdgcn_global_load_lds(
      (const __attribute__((address_space(1))) unsigned int*)g,
      (__attribute__((address_space(3))) unsigned int*)l, 16, 0, 0);
}

// ---------------------------------------------------------------------------
// K1: O(N^2) brute-force rank + at-risk sums (replaces sort+cumsum).
//   rank_i    = #{j : t_j < t_i or (t_j==t_i and j<i)}
//   at_risk_i = sum over complement (incl. self) of exp(clip(lr_j,-10,10))
// grid (32 i-blocks, 16 j-chunks) x 256 thr.
// ---------------------------------------------------------------------------
__global__ void __launch_bounds__(256) k_rank_atrisk(
    const float* __restrict__ times, const float* __restrict__ lr,
    int* __restrict__ rank, float* __restrict__ at_risk) {
  __shared__ __align__(16) float st[512];
  __shared__ __align__(16) float se[512];
  const int tid = threadIdx.x;
  const int i = blockIdx.x * 256 + tid;
  const int jbase = blockIdx.y * 512;
  for (int p = tid; p < 512; p += 256) {
    float t = times[jbase + p];
    float l = lr[jbase + p];
    l = fminf(fmaxf(l, -10.f), 10.f);
    st[p] = t;
    se[p] = __expf(l);
  }
  __syncthreads();
  const float ti = times[i];
  int rk = 0;
  float ar = 0.f;
  for (int p4 = 0; p4 < 512; p4 += 4) {
    float4 tv = *(const float4*)&st[p4];
    float4 ev = *(const float4*)&se[p4];
    const int j0 = jbase + p4;
#define K1_STEP(c, jo)                                              \
    {                                                               \
      bool c1 = (c < ti) || ((c == ti) && ((j0 + jo) < i));         \
      rk += c1 ? 1 : 0;                                             \
      ar += c1 ? 0.f : ((jo == 0) ? ev.x : (jo == 1) ? ev.y         \
                         : (jo == 2) ? ev.z : ev.w);                \
    }
    K1_STEP(tv.x, 0) K1_STEP(tv.y, 1) K1_STEP(tv.z, 2) K1_STEP(tv.w, 3)
#undef K1_STEP
  }
  atomicAdd(&rank[i], rk);
  atomicAdd(&at_risk[i], ar);
}

// ---------------------------------------------------------------------------
// K2: per-row (one wave per row): norms, cos-sim, Cox li, normalize -> fp8
// -> scatter into rank-permuted packed layout. Block-reduce + slot atomics.
// Lane covers k = lane*4..+3: kp=lane>>4, h=(lane>>3)&1, q=(lane>>1)&3,
// j0=(lane&1)*4 -> offset ((kp*4+q)*NN + r)*16 + h*8 + j0.
// ---------------------------------------------------------------------------
__global__ void __launch_bounds__(256) k_rows(
    const float* __restrict__ lr, const int* __restrict__ censor,
    const float* __restrict__ wsi, const float* __restrict__ omic,
    const int* __restrict__ rank, const float* __restrict__ at_risk,
    unsigned char* __restrict__ pw, unsigned char* __restrict__ po,
    float* __restrict__ slots) {
  __shared__ float red[4][3];
  const int tid = threadIdx.x;
  const int lane = tid & 63;
  const int wv = tid >> 6;
  const int i = blockIdx.x * 4 + wv;
  const float4 w = ((const float4*)(wsi + (size_t)i * DD))[lane];
  const float4 o = ((const float4*)(omic + (size_t)i * DD))[lane];
  float nw = w.x * w.x + w.y * w.y + w.z * w.z + w.w * w.w;
  float no = o.x * o.x + o.y * o.y + o.z * o.z + o.w * o.w;
  float dd = w.x * o.x + w.y * o.y + w.z * o.z + w.w * o.w;
  for (int m = 1; m < 64; m <<= 1) {
    nw += __shfl_xor(nw, m);
    no += __shfl_xor(no, m);
    dd += __shfl_xor(dd, m);
  }
  const float nws = sqrtf(nw), nos = sqrtf(no);
  if (lane == 0) {
    float c = dd / (fmaxf(nws, 1e-8f) * fmaxf(nos, 1e-8f));
    c = fminf(fmaxf(c, -1.f), 1.f);
    float l = fminf(fmaxf(lr[i], -10.f), 10.f);
    float li = l - logf(at_risk[i] + 1e-15f);
    bool cen = (censor[i] == 1);
    red[wv][0] = cen ? li : 0.f;
    red[wv][1] = cen ? 1.f : 0.f;
    red[wv][2] = 1.f - c;
  }
  const int r = rank[i]; // permuted row; rank>>11 == risk group
  const float iw = 1.f / fmaxf(nws, 1e-12f);
  const float io = 1.f / fmaxf(nos, 1e-12f);
  int zw = __builtin_amdgcn_cvt_pk_fp8_f32(w.x * iw, w.y * iw, 0, false);
  zw = __builtin_amdgcn_cvt_pk_fp8_f32(w.z * iw, w.w * iw, zw, true);
  int zo = __builtin_amdgcn_cvt_pk_fp8_f32(o.x * io, o.y * io, 0, false);
  zo = __builtin_amdgcn_cvt_pk_fp8_f32(o.z * io, o.w * io, zo, true);
  const size_t off = ((size_t)((lane >> 4) * 4 + ((lane >> 1) & 3)) * NN + r) * 16
                     + ((lane >> 3) & 1) * 8 + (lane & 1) * 4;
  *(unsigned int*)(pw + off) = (unsigned int)zw;
  *(unsigned int*)(po + off) = (unsigned int)zo;
  __syncthreads();
  if (tid < 3) {
    float v = red[0][tid] + red[1][tid] + red[2][tid] + red[3][tid];
    atomicAdd(&slots[tid * NSLOT + (blockIdx.x & (NSLOT - 1))], v);
  }
}

// ---------------------------------------------------------------------------
// K3: contrastive exp-sums, fp8. grid (16 cb, 32 rb, 2 mz) x 256 thr,
// launch_bounds(256,3) -> 168-reg budget, 3 blocks/CU (12 waves/CU).
// Block = 256 rows x 512 cols (8 stages x 64 cols). Wave owns 64 rows:
// afrag[4][4] i32x4 = 64 regs resident. B double-buffered LDS 2 x 16 KB
// via global_load_lds (wave stages 4 KB/stage = 4 chunks).
//
// LDS stage layout: pairbase(ct,kp) = (ct*4+kp)*1024; lane l holds 16 B =
// frag(2kp) 8B || frag(2kp+1) 8B at pairbase + l*16 -> ds_read_b128
// lane-linear (conflict-free). DMA chunk u=(wv*4+p)*64+lane: byte u*16 ->
// ct=u>>8, kp=(u>>6)&3, q=(u>>4)&3, lo=u&15; src = pk+((kp*4+q)*NN+col)*16,
// col = colstart + ct*16 + lo -> lands exactly frag-pair-linear.
// Group constant per block: g = cb>>2.
// ---------------------------------------------------------------------------
__global__ void __launch_bounds__(256, 3) k_contrast(
    const unsigned char* __restrict__ pw, const unsigned char* __restrict__ po,
    float* __restrict__ gsum) {
  __shared__ __align__(16) unsigned char sbuf[2][16384]; // 2 x 16 KB
  const int tid = threadIdx.x;
  const int lane = tid & 63;
  const int wv = tid >> 6;                 // 0..3
  const int lo = lane & 15, q = lane >> 4; // MFMA frag coords
  const int cb = blockIdx.x, rb = blockIdx.y, mz = blockIdx.z;
  const unsigned char* __restrict__ pk = (mz == 0) ? pw : po;
  const int rowbase = rb * 256 + wv * 64;
  const int colstart = cb * 512;
  const int g = cb >> 2;

  // A fragments: 4 row-tiles x 4 kp-pairs x 16 B = 64 regs, resident
  i32x4 afrag[4][4];
#pragma unroll
  for (int rt = 0; rt < 4; ++rt) {
    const size_t row = rowbase + rt * 16 + lo;
#pragma unroll
    for (int kp = 0; kp < 4; ++kp)
      afrag[rt][kp] = *(const i32x4*)(pk + ((size_t)(kp * 4 + q) * NN + row) * 16);
  }

  // per-lane DMA sources, 4 chunks/wave (advance +1024 B per stage = +64 cols)
  const unsigned char* gsrc[4];
#pragma unroll
  for (int p = 0; p < 4; ++p) {
    const int u = (wv * 4 + p) * 64 + lane;
    gsrc[p] = pk + ((size_t)(((u >> 6) & 3) * 4 + ((u >> 4) & 3)) * NN
                    + colstart + (u >> 8) * 16 + (u & 15)) * 16;
  }
  unsigned char* const ldb = &sbuf[0][(size_t)wv * 4096];

#pragma unroll
  for (int p = 0; p < 4; ++p) gl_lds16(gsrc[p], ldb + p * 1024);
  __syncthreads();

  float s[4][4] = {{0.f}};

#pragma unroll 1
  for (int st = 0; st < 8; ++st) {
    if (st < 7) { // async-prefetch next stage into other buffer
      const size_t adv = (size_t)(st + 1) * 1024;
      const size_t bofs = ((st + 1) & 1) ? 16384 : 0;
#pragma unroll
      for (int p = 0; p < 4; ++p) gl_lds16(gsrc[p] + adv, ldb + bofs + p * 1024);
    }
    const unsigned char* buf = &sbuf[st & 1][0];
    const bool diagw = (rowbase == colstart + st * 64);
#pragma unroll
    for (int ct = 0; ct < 4; ++ct) {
      f32x4 acc[4];
#pragma unroll
      for (int rt = 0; rt < 4; ++rt) { f32x4 z = {0.f, 0.f, 0.f, 0.f}; acc[rt] = z; }
#pragma unroll
      for (int kh = 0; kh < 2; ++kh) { // kp pairs {0,1} then {2,3}
        l64x2 b0 = __builtin_bit_cast(l64x2,
            *(const i32x4*)&buf[(ct * 4 + kh * 2 + 0) * 1024 + lane * 16]);
        l64x2 b1 = __builtin_bit_cast(l64x2,
            *(const i32x4*)&buf[(ct * 4 + kh * 2 + 1) * 1024 + lane * 16]);
#pragma unroll
        for (int rt = 0; rt < 4; ++rt) {
          l64x2 a0 = __builtin_bit_cast(l64x2, afrag[rt][kh * 2 + 0]);
          acc[rt] = __builtin_amdgcn_mfma_f32_16x16x32_fp8_fp8(a0[0], b0[0], acc[rt], 0, 0, 0);
          acc[rt] = __builtin_amdgcn_mfma_f32_16x16x32_fp8_fp8(a0[1], b0[1], acc[rt], 0, 0, 0);
        }
#pragma unroll
        for (int rt = 0; rt < 4; ++rt) {
          l64x2 a1 = __builtin_bit_cast(l64x2, afrag[rt][kh * 2 + 1]);
          acc[rt] = __builtin_amdgcn_mfma_f32_16x16x32_fp8_fp8(a1[0], b1[0], acc[rt], 0, 0, 0);
          acc[rt] = __builtin_amdgcn_mfma_f32_16x16x32_fp8_fp8(a1[1], b1[1], acc[rt], 0, 0, 0);
        }
      }
      // epilogue: exp(sim-10), sim = dot/0.1 (unit vectors => sim<=10)
      if (diagw) {
#pragma unroll
        for (int rt = 0; rt < 4; ++rt)
#pragma unroll
          for (int r = 0; r < 4; ++r) {
            float e = __expf(fmaf(acc[rt][r], 10.f, -10.f));
            if (rt == ct && lo == q * 4 + r) e = 0.f; // exact diagonal
            s[rt][r] += e;
          }
      } else {
#pragma unroll
        for (int rt = 0; rt < 4; ++rt)
#pragma unroll
          for (int r = 0; r < 4; ++r)
            s[rt][r] += __expf(fmaf(acc[rt][r], 10.f, -10.f));
      }
    }
    __syncthreads();
  }

  // flush: reduce over 16 col-lanes, one atomic per (row, group)
#pragma unroll
  for (int rt = 0; rt < 4; ++rt)
#pragma unroll
    for (int r = 0; r < 4; ++r) {
      float v = s[rt][r];
      v += __shfl_xor(v, 1); v += __shfl_xor(v, 2);
      v += __shfl_xor(v, 4); v += __shfl_xor(v, 8);
      if (lo == 0) {
        const int row = rowbase + rt * 16 + q * 4 + r; // C/D: row=(lane>>4)*4+reg
        atomicAdd(&gsum[((size_t)mz * NN + row) * 4 + g], v);
      }
    }
}

// ---------------------------------------------------------------------------
// K3b: per-row LSE difference + reduce. loss = log(sum_all) - log(sum_pos).
// ---------------------------------------------------------------------------
__global__ void __launch_bounds__(256) k_lse(
    const float* __restrict__ gsum, float* __restrict__ slots) {
  __shared__ float r4[4];
  const int tid = threadIdx.x;
  const int lane = tid & 63, wv = tid >> 6;
  const int idx = blockIdx.x * 256 + tid; // (matrix, row) flattened
  const float4 v = ((const float4*)gsum)[idx];
  const int row = idx & (NN - 1);
  const int gg = row >> 11; // group of permuted row
  const float sg = (gg == 0) ? v.x : (gg == 1) ? v.y : (gg == 2) ? v.z : v.w;
  float loss = logf(v.x + v.y + v.z + v.w) - logf(sg);
  for (int m = 1; m < 64; m <<= 1) loss += __shfl_xor(loss, m);
  if (lane == 0) r4[wv] = loss;
  __syncthreads();
  if (tid == 0)
    atomicAdd(&slots[3 * NSLOT + (blockIdx.x & (NSLOT - 1))],
              r4[0] + r4[1] + r4[2] + r4[3]);
}

// ---------------------------------------------------------------------------
// K4: reduce slots, combine scalar.
// ---------------------------------------------------------------------------
__global__ void k_final(const float* __restrict__ slots, float* __restrict__ out) {
  const int lane = threadIdx.x & 63;
  float cox_s = (lane < NSLOT) ? slots[0 * NSLOT + lane] : 0.f;
  float cnt_s = (lane < NSLOT) ? slots[1 * NSLOT + lane] : 0.f;
  float sim_s = (lane < NSLOT) ? slots[2 * NSLOT + lane] : 0.f;
  float con_s = (lane < NSLOT) ? slots[3 * NSLOT + lane] : 0.f;
  for (int m = 1; m < 64; m <<= 1) {
    cox_s += __shfl_xor(cox_s, m);
    cnt_s += __shfl_xor(cnt_s, m);
    sim_s += __shfl_xor(sim_s, m);
    con_s += __shfl_xor(con_s, m);
  }
  if (lane == 0) {
    float cnt = fmaxf(cnt_s, 1.f);
    float cox = -cox_s / cnt;
    float sim = sim_s / (float)NN;
    float contrast = 0.1f * 0.5f * con_s / (float)NN;
    out[0] = cox + sim + contrast;
  }
}

extern "C" void kernel_launch(void* const* d_in, const int* in_sizes, int n_in,
                              void* d_out, int out_size, void* d_ws, size_t ws_size,
                              hipStream_t stream) {
  const float* lr = (const float*)d_in[0];
  const float* times = (const float*)d_in[1];
  const int* censor = (const int*)d_in[2];
  const float* wsi = (const float*)d_in[3];
  const float* omic = (const float*)d_in[4];
  float* out = (float*)d_out;

  char* ws = (char*)d_ws;
  int* rank = (int*)ws;
  float* at_risk = (float*)(ws + 32768);
  float* slots = (float*)(ws + 65536);
  float* gsum = (float*)(ws + 66560);
  unsigned char* pw = (unsigned char*)(ws + 393216);
  unsigned char* po = (unsigned char*)(ws + 393216 + 2097152);

  // one memset covers rank, at_risk, slots, gsum
  (void)hipMemsetAsync(d_ws, 0, 328704, stream);
  k_rank_atrisk<<<dim3(32, 16), 256, 0, stream>>>(times, lr, rank, at_risk);
  k_rows<<<2048, 256, 0, stream>>>(lr, censor, wsi, omic, rank, at_risk, pw, po, slots);
  k_contrast<<<dim3(16, 32, 2), 256, 0, stream>>>(pw, po, gsum);
  k_lse<<<64, 256, 0, stream>>>(gsum, slots);
  k_final<<<1, 64, 0, stream>>>(slots, out);
}

// Round 9
// 156.956 us; speedup vs baseline: 1.6812x; 1.0812x over previous
//
#include <hip/hip_runtime.h>

// JointLoss on MI355X. N=8192, D=256. Output: 1 fp32 scalar.
//
// ws layout (bytes):
//   [0,      32768)   pslots[2048][4] float: per-k_rows-block partials (cox,cnt,sim)
//   [32768,  294912)  gsum[2][8192][4] float (per matrix,row,group exp-sums)
//   [294912, +2M)     packed wsi fp8 e4m3: byte ((kp*4+q)*N + row)*16 + h*8 + j
//                     holds emb[row][k], k = (2kp+h)*32 + q*8 + j
//   [294912+2M, +4M)  packed omic fp8 (same layout)
//
// R1: same-address atomics serialize -> spread/partial-write instead.
// R2: 64-row blocks streamed 1 GB of B from LLC -> latency-bound.
// R3/R7: unified VGPR+AGPR budget: ask for more waves than regs allow -> spill.
// R5: LDS-BW + exp-VALU bound -> fp8 (half bytes, same MFMA rate).
// R8: spill fixed; k_contrast 61us = 43% MfmaUtil vs true 28us MFMA floor
//     (earlier "8us floor" was arithmetic error). Limiter: 2 waves/SIMD
//     (AGPRs hidden from VGPR_Count) -> pipe idles during epilogue.
//     Also: constant ~108us = 5 small dispatches + inter-dispatch gaps.
// Now: 32 rows/wave (~100 regs) -> 4 blocks/CU; 3 dispatches total
//     (rank-scan fused into k_rows; lse+final fused; memset eliminated).

#define NN 8192
#define DD 256

typedef __attribute__((ext_vector_type(4))) float f32x4;
typedef __attribute__((ext_vector_type(4))) int i32x4;
typedef __attribute__((ext_vector_type(2))) long l64x2;

__device__ inline void gl_lds16(const void* g, void* l) {
  // async 16B/lane global->LDS; LDS dst must be wave-uniform base + lane*16
  __builtin_amdgcn_global_load_lds(
      (const __attribute__((address_space(1))) unsigned int*)g,
      (__attribute__((address_space(3))) unsigned int*)l, 16, 0, 0);
}

// ---------------------------------------------------------------------------
// K1 (fused): per-row everything. grid 2048 x 256 thr (4 waves, 1 row each).
//  - rank_i / at_risk_i by full O(N) scan per wave over LDS-staged chunks
//    (no atomics, no init): rank_i = #{j: t_j<t_i or (t_j==t_i and j<i)},
//    at_risk_i = sum over complement incl self of exp(clip(lr_j)).
//  - norms / cos-sim / Cox li -> NON-atomic per-block partial in pslots[blk].
//  - normalize -> fp8 -> scatter into rank-permuted packed layout.
//  - first 64 blocks also zero gsum (runs before k_contrast in-stream).
// ---------------------------------------------------------------------------
__global__ void __launch_bounds__(256) k_rows(
    const float* __restrict__ lr, const float* __restrict__ times,
    const int* __restrict__ censor,
    const float* __restrict__ wsi, const float* __restrict__ omic,
    unsigned char* __restrict__ pw, unsigned char* __restrict__ po,
    float* __restrict__ pslots, float* __restrict__ gsum) {
  __shared__ __align__(16) float st[1024];
  __shared__ __align__(16) float se[1024];
  __shared__ float red[4][3];
  const int tid = threadIdx.x;
  const int lane = tid & 63;
  const int wv = tid >> 6;
  const int i = blockIdx.x * 4 + wv;

  if (blockIdx.x < 64) { // zero gsum (65536 floats) across first 64 blocks
    ((f32x4*)gsum)[blockIdx.x * 256 + tid] = (f32x4){0.f, 0.f, 0.f, 0.f};
  }

  // embeddings: norms + dot via wave shuffle
  const float4 w = ((const float4*)(wsi + (size_t)i * DD))[lane];
  const float4 o = ((const float4*)(omic + (size_t)i * DD))[lane];
  float nw = w.x * w.x + w.y * w.y + w.z * w.z + w.w * w.w;
  float no = o.x * o.x + o.y * o.y + o.z * o.z + o.w * o.w;
  float dd = w.x * o.x + w.y * o.y + w.z * o.z + w.w * o.w;
  for (int m = 1; m < 64; m <<= 1) {
    nw += __shfl_xor(nw, m);
    no += __shfl_xor(no, m);
    dd += __shfl_xor(dd, m);
  }
  const float nws = sqrtf(nw), nos = sqrtf(no);

  // rank + at_risk: scan all 8192 j in 8 LDS chunks of 1024
  const float ti = times[i];
  int rk = 0;
  float ar = 0.f;
  for (int c = 0; c < 8; ++c) {
    __syncthreads();
    for (int p = tid; p < 1024; p += 256) {
      float t = times[c * 1024 + p];
      float l = lr[c * 1024 + p];
      st[p] = t;
      se[p] = __expf(fminf(fmaxf(l, -10.f), 10.f));
    }
    __syncthreads();
#pragma unroll 4
    for (int jt = 0; jt < 16; ++jt) {
      const int p = jt * 64 + lane;
      const float t = st[p];
      const float e = se[p];
      const bool c1 = (t < ti) || ((t == ti) && ((c * 1024 + p) < i));
      rk += c1 ? 1 : 0;
      ar += c1 ? 0.f : e;
    }
  }
  for (int m = 1; m < 64; m <<= 1) {
    rk += __shfl_xor(rk, m);
    ar += __shfl_xor(ar, m);
  }

  if (lane == 0) {
    float c = dd / (fmaxf(nws, 1e-8f) * fmaxf(nos, 1e-8f));
    c = fminf(fmaxf(c, -1.f), 1.f);
    float l = fminf(fmaxf(lr[i], -10.f), 10.f);
    float li = l - logf(ar + 1e-15f);
    bool cen = (censor[i] == 1);
    red[wv][0] = cen ? li : 0.f;
    red[wv][1] = cen ? 1.f : 0.f;
    red[wv][2] = 1.f - c;
  }

  // normalize -> fp8 -> rank-permuted packed scatter
  // lane covers k = lane*4..+3: kp=lane>>4, h=(lane>>3)&1, q=(lane>>1)&3,
  // j0=(lane&1)*4 -> offset ((kp*4+q)*NN + r)*16 + h*8 + j0.
  const int r = rk; // permuted row; r>>11 == risk group
  const float iw = 1.f / fmaxf(nws, 1e-12f);
  const float io = 1.f / fmaxf(nos, 1e-12f);
  int zw = __builtin_amdgcn_cvt_pk_fp8_f32(w.x * iw, w.y * iw, 0, false);
  zw = __builtin_amdgcn_cvt_pk_fp8_f32(w.z * iw, w.w * iw, zw, true);
  int zo = __builtin_amdgcn_cvt_pk_fp8_f32(o.x * io, o.y * io, 0, false);
  zo = __builtin_amdgcn_cvt_pk_fp8_f32(o.z * io, o.w * io, zo, true);
  const size_t off = ((size_t)((lane >> 4) * 4 + ((lane >> 1) & 3)) * NN + r) * 16
                     + ((lane >> 3) & 1) * 8 + (lane & 1) * 4;
  *(unsigned int*)(pw + off) = (unsigned int)zw;
  *(unsigned int*)(po + off) = (unsigned int)zo;
  __syncthreads();
  if (tid < 3) { // non-atomic per-block partial (every slot written -> no init)
    pslots[blockIdx.x * 4 + tid] =
        red[0][tid] + red[1][tid] + red[2][tid] + red[3][tid];
  }
}

// ---------------------------------------------------------------------------
// K2: contrastive exp-sums, fp8. grid (16 cb, 64 rb, 2 mz) x 256 thr,
// launch_bounds(256,4) -> 128-reg unified budget, 4 blocks/CU (16 waves/CU).
// Block = 128 rows x 512 cols (8 stages x 64 cols). Wave owns 32 rows:
// afrag[2][4] i32x4 = 32 regs resident (+acc 8 + s 8 + ptrs ~20 => ~100).
// B double-buffered LDS 2 x 16 KB via global_load_lds (4 chunks/wave/stage).
//
// LDS stage layout: pairbase(ct,kp) = (ct*4+kp)*1024; lane l holds 16 B =
// frag(2kp) 8B || frag(2kp+1) 8B at pairbase + l*16 -> ds_read_b128
// lane-linear (conflict-free). DMA chunk u=(wv*4+p)*64+lane: byte u*16 ->
// ct=u>>8, kp=(u>>6)&3, q=(u>>4)&3, lo=u&15; src = pk+((kp*4+q)*NN+col)*16,
// col = colstart + ct*16 + lo -> lands exactly frag-pair-linear.
// Group constant per block: g = cb>>2. Diagonal: wave rows are a 32-row
// half of a 64-col window -> excl when ct==(wv&1)*2+rt && lo==q*4+r.
// ---------------------------------------------------------------------------
__global__ void __launch_bounds__(256, 4) k_contrast(
    const unsigned char* __restrict__ pw, const unsigned char* __restrict__ po,
    float* __restrict__ gsum) {
  __shared__ __align__(16) unsigned char sbuf[2][16384]; // 2 x 16 KB
  const int tid = threadIdx.x;
  const int lane = tid & 63;
  const int wv = tid >> 6;                 // 0..3
  const int lo = lane & 15, q = lane >> 4; // MFMA frag coords
  const int cb = blockIdx.x, rb = blockIdx.y, mz = blockIdx.z;
  const unsigned char* __restrict__ pk = (mz == 0) ? pw : po;
  const int rowbase = rb * 128 + wv * 32;
  const int colstart = cb * 512;
  const int g = cb >> 2;

  // A fragments: 2 row-tiles x 4 kp-pairs x 16 B = 32 regs, resident
  i32x4 afrag[2][4];
#pragma unroll
  for (int rt = 0; rt < 2; ++rt) {
    const size_t row = rowbase + rt * 16 + lo;
#pragma unroll
    for (int kp = 0; kp < 4; ++kp)
      afrag[rt][kp] = *(const i32x4*)(pk + ((size_t)(kp * 4 + q) * NN + row) * 16);
  }

  // per-lane DMA sources, 4 chunks/wave (advance +1024 B per stage = +64 cols)
  const unsigned char* gsrc[4];
#pragma unroll
  for (int p = 0; p < 4; ++p) {
    const int u = (wv * 4 + p) * 64 + lane;
    gsrc[p] = pk + ((size_t)(((u >> 6) & 3) * 4 + ((u >> 4) & 3)) * NN
                    + colstart + (u >> 8) * 16 + (u & 15)) * 16;
  }
  unsigned char* const ldb = &sbuf[0][(size_t)wv * 4096];

#pragma unroll
  for (int p = 0; p < 4; ++p) gl_lds16(gsrc[p], ldb + p * 1024);
  __syncthreads();

  float s[2][4] = {{0.f}};
  const int dctbase = (wv & 1) * 2; // wave's 32 rows within the 64-col window

#pragma unroll 1
  for (int st = 0; st < 8; ++st) {
    if (st < 7) { // async-prefetch next stage into other buffer
      const size_t adv = (size_t)(st + 1) * 1024;
      const size_t bofs = ((st + 1) & 1) ? 16384 : 0;
#pragma unroll
      for (int p = 0; p < 4; ++p) gl_lds16(gsrc[p] + adv, ldb + bofs + p * 1024);
    }
    const unsigned char* buf = &sbuf[st & 1][0];
    const bool diagw = ((rowbase >> 6) == ((colstart + st * 64) >> 6));
#pragma unroll
    for (int ct = 0; ct < 4; ++ct) {
      f32x4 a0 = {0.f, 0.f, 0.f, 0.f}, a1 = {0.f, 0.f, 0.f, 0.f};
#pragma unroll
      for (int kh = 0; kh < 2; ++kh) { // kp pairs {0,1} then {2,3}
        l64x2 b0 = __builtin_bit_cast(l64x2,
            *(const i32x4*)&buf[(ct * 4 + kh * 2 + 0) * 1024 + lane * 16]);
        l64x2 b1 = __builtin_bit_cast(l64x2,
            *(const i32x4*)&buf[(ct * 4 + kh * 2 + 1) * 1024 + lane * 16]);
        l64x2 x0 = __builtin_bit_cast(l64x2, afrag[0][kh * 2 + 0]);
        l64x2 x1 = __builtin_bit_cast(l64x2, afrag[0][kh * 2 + 1]);
        l64x2 y0 = __builtin_bit_cast(l64x2, afrag[1][kh * 2 + 0]);
        l64x2 y1 = __builtin_bit_cast(l64x2, afrag[1][kh * 2 + 1]);
        a0 = __builtin_amdgcn_mfma_f32_16x16x32_fp8_fp8(x0[0], b0[0], a0, 0, 0, 0);
        a1 = __builtin_amdgcn_mfma_f32_16x16x32_fp8_fp8(y0[0], b0[0], a1, 0, 0, 0);
        a0 = __builtin_amdgcn_mfma_f32_16x16x32_fp8_fp8(x0[1], b0[1], a0, 0, 0, 0);
        a1 = __builtin_amdgcn_mfma_f32_16x16x32_fp8_fp8(y0[1], b0[1], a1, 0, 0, 0);
        a0 = __builtin_amdgcn_mfma_f32_16x16x32_fp8_fp8(x1[0], b1[0], a0, 0, 0, 0);
        a1 = __builtin_amdgcn_mfma_f32_16x16x32_fp8_fp8(y1[0], b1[0], a1, 0, 0, 0);
        a0 = __builtin_amdgcn_mfma_f32_16x16x32_fp8_fp8(x1[1], b1[1], a0, 0, 0, 0);
        a1 = __builtin_amdgcn_mfma_f32_16x16x32_fp8_fp8(y1[1], b1[1], a1, 0, 0, 0);
      }
      // epilogue: exp(sim-10), sim = dot/0.1 (unit vectors => sim<=10)
      if (diagw) {
#pragma unroll
        for (int r = 0; r < 4; ++r) {
          float e0 = __expf(fmaf(a0[r], 10.f, -10.f));
          float e1 = __expf(fmaf(a1[r], 10.f, -10.f));
          if (ct == dctbase + 0 && lo == q * 4 + r) e0 = 0.f; // exact diagonal
          if (ct == dctbase + 1 && lo == q * 4 + r) e1 = 0.f;
          s[0][r] += e0;
          s[1][r] += e1;
        }
      } else {
#pragma unroll
        for (int r = 0; r < 4; ++r) {
          s[0][r] += __expf(fmaf(a0[r], 10.f, -10.f));
          s[1][r] += __expf(fmaf(a1[r], 10.f, -10.f));
        }
      }
    }
    __syncthreads();
  }

  // flush: reduce over 16 col-lanes, one atomic per (row, group)
#pragma unroll
  for (int rt = 0; rt < 2; ++rt)
#pragma unroll
    for (int r = 0; r < 4; ++r) {
      float v = s[rt][r];
      v += __shfl_xor(v, 1); v += __shfl_xor(v, 2);
      v += __shfl_xor(v, 4); v += __shfl_xor(v, 8);
      if (lo == 0) {
        const int row = rowbase + rt * 16 + q * 4 + r; // C/D: row=(lane>>4)*4+reg
        atomicAdd(&gsum[((size_t)mz * NN + row) * 4 + g], v);
      }
    }
}

// ---------------------------------------------------------------------------
// K3: finale. One block, 1024 thr. Reduces pslots (cox,cnt,sim), computes
// per-row LSE differences from gsum, combines the scalar.
// ---------------------------------------------------------------------------
__global__ void __launch_bounds__(1024) k_finale(
    const float* __restrict__ pslots, const float* __restrict__ gsum,
    float* __restrict__ out) {
  __shared__ float rsum[16][4];
  const int tid = threadIdx.x;
  const int lane = tid & 63, wv = tid >> 6;
  float cox = 0.f, cnt = 0.f, sim = 0.f, con = 0.f;
  for (int b = tid; b < 2048; b += 1024) {
    const float4 v = ((const float4*)pslots)[b];
    cox += v.x; cnt += v.y; sim += v.z;
  }
  for (int idx = tid; idx < 2 * NN; idx += 1024) {
    const float4 v = ((const float4*)gsum)[idx];
    const int row = idx & (NN - 1);
    const int gg = row >> 11; // group of permuted row
    const float sg = (gg == 0) ? v.x : (gg == 1) ? v.y : (gg == 2) ? v.z : v.w;
    con += logf(v.x + v.y + v.z + v.w) - logf(sg); // fixed shifts cancel
  }
  for (int m = 1; m < 64; m <<= 1) {
    cox += __shfl_xor(cox, m);
    cnt += __shfl_xor(cnt, m);
    sim += __shfl_xor(sim, m);
    con += __shfl_xor(con, m);
  }
  if (lane == 0) {
    rsum[wv][0] = cox; rsum[wv][1] = cnt; rsum[wv][2] = sim; rsum[wv][3] = con;
  }
  __syncthreads();
  if (tid == 0) {
    float c0 = 0.f, c1 = 0.f, c2 = 0.f, c3 = 0.f;
    for (int k = 0; k < 16; ++k) {
      c0 += rsum[k][0]; c1 += rsum[k][1]; c2 += rsum[k][2]; c3 += rsum[k][3];
    }
    out[0] = -c0 / fmaxf(c1, 1.f) + c2 / (float)NN
             + 0.1f * 0.5f * c3 / (float)NN;
  }
}

extern "C" void kernel_launch(void* const* d_in, const int* in_sizes, int n_in,
                              void* d_out, int out_size, void* d_ws, size_t ws_size,
                              hipStream_t stream) {
  const float* lr = (const float*)d_in[0];
  const float* times = (const float*)d_in[1];
  const int* censor = (const int*)d_in[2];
  const float* wsi = (const float*)d_in[3];
  const float* omic = (const float*)d_in[4];
  float* out = (float*)d_out;

  char* ws = (char*)d_ws;
  float* pslots = (float*)ws;
  float* gsum = (float*)(ws + 32768);
  unsigned char* pw = (unsigned char*)(ws + 294912);
  unsigned char* po = (unsigned char*)(ws + 294912 + 2097152);

  k_rows<<<2048, 256, 0, stream>>>(lr, times, censor, wsi, omic, pw, po, pslots, gsum);
  k_contrast<<<dim3(16, 64, 2), 256, 0, stream>>>(pw, po, gsum);
  k_finale<<<1, 1024, 0, stream>>>(pslots, gsum, out);
}

// Round 10
// 145.961 us; speedup vs baseline: 1.8078x; 1.0753x over previous
//
#include <hip/hip_runtime.h>

// JointLoss on MI355X. N=8192, D=256. Output: 1 fp32 scalar.
//
// ws layout (bytes):
//   [0,      32768)   pslots[2048][4] float: per-k_rows-block partials (cox,cnt,sim)
//   [32768,  294912)  gsum[2][8192][4] float (per matrix,row,group exp-sums)
//   [294912, +2M)     packed wsi fp8 e4m3 for MX K=128 MFMA:
//                     byte ((ks*4+q)*N + row)*32 + j holds emb[row][k],
//                     k = ks*128 + q*32 + j   (ks<2, q<4, j<32)
//   [294912+2M, +4M)  packed omic fp8 (same layout)
//
// R1: same-address atomics serialize -> spread/partial-write instead.
// R2: tiny row-blocks streamed 1 GB of B from LLC -> latency-bound.
// R3/R7: unified VGPR+AGPR budget: over-ask waves -> spill (HBM scratch).
// R5: LDS-BW + exp-VALU bound -> fp8 (half bytes, same MFMA rate).
// R8/R9: spill fixed, 4 blk/CU; 54us = MFMA 50% + VALU 50% pipe-saturated;
//     fp8 16x16x32 matrix floor ~33us. Constant ~103us non-contrast time is
//     harness reset overhead + small kernels, invariant to dispatch count.
// Now: MX-scaled fp8 K=128 (unit scales) -> 2x matrix rate, floor ~15us.

#define NN 8192
#define DD 256

typedef __attribute__((ext_vector_type(4))) float f32x4;
typedef __attribute__((ext_vector_type(4))) int i32x4;
typedef __attribute__((ext_vector_type(8))) int i32x8;

__device__ inline void gl_lds16(const void* g, void* l) {
  // async 16B/lane global->LDS; LDS dst must be wave-uniform base + lane*16
  __builtin_amdgcn_global_load_lds(
      (const __attribute__((address_space(1))) unsigned int*)g,
      (__attribute__((address_space(3))) unsigned int*)l, 16, 0, 0);
}

// ---------------------------------------------------------------------------
// K1 (fused): per-row everything. grid 2048 x 256 thr (4 waves, 1 row each).
//  - rank_i / at_risk_i by full O(N) scan per wave over LDS-staged chunks
//    (no atomics, no init): rank_i = #{j: t_j<t_i or (t_j==t_i and j<i)},
//    at_risk_i = sum over complement incl self of exp(clip(lr_j)).
//  - norms / cos-sim / Cox li -> NON-atomic per-block partial in pslots[blk].
//  - normalize -> fp8 -> scatter into rank-permuted MX-packed layout.
//  - first 64 blocks also zero gsum (runs before k_contrast in-stream).
// ---------------------------------------------------------------------------
__global__ void __launch_bounds__(256) k_rows(
    const float* __restrict__ lr, const float* __restrict__ times,
    const int* __restrict__ censor,
    const float* __restrict__ wsi, const float* __restrict__ omic,
    unsigned char* __restrict__ pw, unsigned char* __restrict__ po,
    float* __restrict__ pslots, float* __restrict__ gsum) {
  __shared__ __align__(16) float st[1024];
  __shared__ __align__(16) float se[1024];
  __shared__ float red[4][3];
  const int tid = threadIdx.x;
  const int lane = tid & 63;
  const int wv = tid >> 6;
  const int i = blockIdx.x * 4 + wv;

  if (blockIdx.x < 64) { // zero gsum (65536 floats) across first 64 blocks
    ((f32x4*)gsum)[blockIdx.x * 256 + tid] = (f32x4){0.f, 0.f, 0.f, 0.f};
  }

  // embeddings: norms + dot via wave shuffle
  const float4 w = ((const float4*)(wsi + (size_t)i * DD))[lane];
  const float4 o = ((const float4*)(omic + (size_t)i * DD))[lane];
  float nw = w.x * w.x + w.y * w.y + w.z * w.z + w.w * w.w;
  float no = o.x * o.x + o.y * o.y + o.z * o.z + o.w * o.w;
  float dd = w.x * o.x + w.y * o.y + w.z * o.z + w.w * o.w;
  for (int m = 1; m < 64; m <<= 1) {
    nw += __shfl_xor(nw, m);
    no += __shfl_xor(no, m);
    dd += __shfl_xor(dd, m);
  }
  const float nws = sqrtf(nw), nos = sqrtf(no);

  // rank + at_risk: scan all 8192 j in 8 LDS chunks of 1024
  const float ti = times[i];
  int rk = 0;
  float ar = 0.f;
  for (int c = 0; c < 8; ++c) {
    __syncthreads();
    for (int p = tid; p < 1024; p += 256) {
      float t = times[c * 1024 + p];
      float l = lr[c * 1024 + p];
      st[p] = t;
      se[p] = __expf(fminf(fmaxf(l, -10.f), 10.f));
    }
    __syncthreads();
#pragma unroll 4
    for (int jt = 0; jt < 16; ++jt) {
      const int p = jt * 64 + lane;
      const float t = st[p];
      const float e = se[p];
      const bool c1 = (t < ti) || ((t == ti) && ((c * 1024 + p) < i));
      rk += c1 ? 1 : 0;
      ar += c1 ? 0.f : e;
    }
  }
  for (int m = 1; m < 64; m <<= 1) {
    rk += __shfl_xor(rk, m);
    ar += __shfl_xor(ar, m);
  }

  if (lane == 0) {
    float c = dd / (fmaxf(nws, 1e-8f) * fmaxf(nos, 1e-8f));
    c = fminf(fmaxf(c, -1.f), 1.f);
    float l = fminf(fmaxf(lr[i], -10.f), 10.f);
    float li = l - logf(ar + 1e-15f);
    bool cen = (censor[i] == 1);
    red[wv][0] = cen ? li : 0.f;
    red[wv][1] = cen ? 1.f : 0.f;
    red[wv][2] = 1.f - c;
  }

  // normalize -> fp8 -> rank-permuted MX-packed scatter
  // lane covers k = lane*4..+3: ks=lane>>5, q=(lane>>3)&3, j=(lane&7)*4
  // -> offset ((ks*4+q)*NN + r)*32 + j.
  const int r = rk; // permuted row; r>>11 == risk group
  const float iw = 1.f / fmaxf(nws, 1e-12f);
  const float io = 1.f / fmaxf(nos, 1e-12f);
  int zw = __builtin_amdgcn_cvt_pk_fp8_f32(w.x * iw, w.y * iw, 0, false);
  zw = __builtin_amdgcn_cvt_pk_fp8_f32(w.z * iw, w.w * iw, zw, true);
  int zo = __builtin_amdgcn_cvt_pk_fp8_f32(o.x * io, o.y * io, 0, false);
  zo = __builtin_amdgcn_cvt_pk_fp8_f32(o.z * io, o.w * io, zo, true);
  const size_t off = ((size_t)((lane >> 5) * 4 + ((lane >> 3) & 3)) * NN + r) * 32
                     + (lane & 7) * 4;
  *(unsigned int*)(pw + off) = (unsigned int)zw;
  *(unsigned int*)(po + off) = (unsigned int)zo;
  __syncthreads();
  if (tid < 3) { // non-atomic per-block partial (every slot written -> no init)
    pslots[blockIdx.x * 4 + tid] =
        red[0][tid] + red[1][tid] + red[2][tid] + red[3][tid];
  }
}

// ---------------------------------------------------------------------------
// K2: contrastive exp-sums, MX fp8 K=128. grid (16 cb, 64 rb, 2 mz) x 256
// thr, launch_bounds(256,4) -> 128-reg budget, 4 blocks/CU.
// Block = 128 rows x 512 cols (8 stages x 64 cols). Wave owns 32 rows:
// afrag[2 rt][2 ks] i32x8 = 32 regs resident. B double-buffered LDS
// 2 x 16 KB via global_load_lds (4 chunks/wave/stage).
//
// MX operand layout (extends verified 16x16x32 fp8 pattern): lane(q,lo)
// holds 32 B = X[lo][k = ks*128 + q*32 .. +31]; per-lane scale block = 32
// elems, unit scale 0x7F (2^0).
// LDS: region(ct,ks,h) = ((ct*2+ks)*2+h)*1024; lane l holds 16 B
// (k half h) at region + l*16 -> two lane-linear ds_read_b128 per frag,
// conflict-free. DMA chunk u=(wv*4+p)*64+lane writes byte u*16; decode
// ct=u>>8, ks=(u>>7)&1, h=(u>>6)&1, l=u&63 -> src
// pk + ((ks*4+(l>>4))*NN + col)*32 + h*16, col = colstart+ct*16+(l&15).
// Group constant per block: g = cb>>2. Diagonal: wave rows are the
// (wv&1)-half of a 64-col window -> excl when ct==(wv&1)*2+rt && lo==q*4+r.
// ---------------------------------------------------------------------------
__global__ void __launch_bounds__(256, 4) k_contrast(
    const unsigned char* __restrict__ pw, const unsigned char* __restrict__ po,
    float* __restrict__ gsum) {
  __shared__ __align__(16) unsigned char sbuf[2][16384]; // 2 x 16 KB
  const int tid = threadIdx.x;
  const int lane = tid & 63;
  const int wv = tid >> 6;                 // 0..3
  const int lo = lane & 15, q = lane >> 4; // MFMA frag coords
  const int cb = blockIdx.x, rb = blockIdx.y, mz = blockIdx.z;
  const unsigned char* __restrict__ pk = (mz == 0) ? pw : po;
  const int rowbase = rb * 128 + wv * 32;
  const int colstart = cb * 512;
  const int g = cb >> 2;

  // A fragments: 2 row-tiles x 2 K-segments x 32 B = 32 regs, resident
  i32x8 afrag[2][2];
#pragma unroll
  for (int rt = 0; rt < 2; ++rt) {
    const size_t row = rowbase + rt * 16 + lo;
#pragma unroll
    for (int ks = 0; ks < 2; ++ks)
      afrag[rt][ks] = *(const i32x8*)(pk + ((size_t)(ks * 4 + q) * NN + row) * 32);
  }

  // per-lane DMA sources, 4 chunks/wave (advance +2048 B per stage = +64 cols)
  const unsigned char* gsrc[4];
#pragma unroll
  for (int p = 0; p < 4; ++p) {
    const int u = (wv * 4 + p) * 64 + lane;
    const int uct = u >> 8, uks = (u >> 7) & 1, uh = (u >> 6) & 1;
    const int ul = u & 63;
    gsrc[p] = pk + ((size_t)(uks * 4 + (ul >> 4)) * NN
                    + colstart + uct * 16 + (ul & 15)) * 32 + uh * 16;
  }
  unsigned char* const ldb = &sbuf[0][(size_t)wv * 4096];

#pragma unroll
  for (int p = 0; p < 4; ++p) gl_lds16(gsrc[p], ldb + p * 1024);
  __syncthreads();

  float s[2][4] = {{0.f}};
  const int dctbase = (wv & 1) * 2; // wave's 32 rows within the 64-col window

#pragma unroll 1
  for (int st = 0; st < 8; ++st) {
    if (st < 7) { // async-prefetch next stage into other buffer
      const size_t adv = (size_t)(st + 1) * 2048;
      const size_t bofs = ((st + 1) & 1) ? 16384 : 0;
#pragma unroll
      for (int p = 0; p < 4; ++p) gl_lds16(gsrc[p] + adv, ldb + bofs + p * 1024);
    }
    const unsigned char* buf = &sbuf[st & 1][0];
    const bool diagw = ((rowbase >> 6) == ((colstart + st * 64) >> 6));
#pragma unroll
    for (int ct = 0; ct < 4; ++ct) {
      f32x4 a0 = {0.f, 0.f, 0.f, 0.f}, a1 = {0.f, 0.f, 0.f, 0.f};
#pragma unroll
      for (int ks = 0; ks < 2; ++ks) {
        const int rbase = ((ct * 2 + ks) * 2) * 1024 + lane * 16;
        i32x4 blo = *(const i32x4*)&buf[rbase];
        i32x4 bhi = *(const i32x4*)&buf[rbase + 1024];
        i32x8 b = __builtin_shufflevector(blo, bhi, 0, 1, 2, 3, 4, 5, 6, 7);
        // unit scales (E8M0 0x7F = 2^0); fmt 0 = fp8 e4m3 for A and B
        a0 = __builtin_amdgcn_mfma_scale_f32_16x16x128_f8f6f4(
            afrag[0][ks], b, a0, 0, 0, 0, 0x7F, 0, 0x7F);
        a1 = __builtin_amdgcn_mfma_scale_f32_16x16x128_f8f6f4(
            afrag[1][ks], b, a1, 0, 0, 0, 0x7F, 0, 0x7F);
      }
      // epilogue: exp(sim-10) = 2^(14.427*dot - 14.427), sim = dot/0.1 <= 10
      if (diagw) {
#pragma unroll
        for (int r = 0; r < 4; ++r) {
          float e0 = __builtin_amdgcn_exp2f(fmaf(a0[r], 14.4269504f, -14.4269504f));
          float e1 = __builtin_amdgcn_exp2f(fmaf(a1[r], 14.4269504f, -14.4269504f));
          if (ct == dctbase + 0 && lo == q * 4 + r) e0 = 0.f; // exact diagonal
          if (ct == dctbase + 1 && lo == q * 4 + r) e1 = 0.f;
          s[0][r] += e0;
          s[1][r] += e1;
        }
      } else {
#pragma unroll
        for (int r = 0; r < 4; ++r) {
          s[0][r] += __builtin_amdgcn_exp2f(fmaf(a0[r], 14.4269504f, -14.4269504f));
          s[1][r] += __builtin_amdgcn_exp2f(fmaf(a1[r], 14.4269504f, -14.4269504f));
        }
      }
    }
    __syncthreads();
  }

  // flush: reduce over 16 col-lanes, one atomic per (row, group)
#pragma unroll
  for (int rt = 0; rt < 2; ++rt)
#pragma unroll
    for (int r = 0; r < 4; ++r) {
      float v = s[rt][r];
      v += __shfl_xor(v, 1); v += __shfl_xor(v, 2);
      v += __shfl_xor(v, 4); v += __shfl_xor(v, 8);
      if (lo == 0) {
        const int row = rowbase + rt * 16 + q * 4 + r; // C/D: row=(lane>>4)*4+reg
        atomicAdd(&gsum[((size_t)mz * NN + row) * 4 + g], v);
      }
    }
}

// ---------------------------------------------------------------------------
// K3: finale. One block, 1024 thr. Reduces pslots (cox,cnt,sim), computes
// per-row LSE differences from gsum, combines the scalar.
// ---------------------------------------------------------------------------
__global__ void __launch_bounds__(1024) k_finale(
    const float* __restrict__ pslots, const float* __restrict__ gsum,
    float* __restrict__ out) {
  __shared__ float rsum[16][4];
  const int tid = threadIdx.x;
  const int lane = tid & 63, wv = tid >> 6;
  float cox = 0.f, cnt = 0.f, sim = 0.f, con = 0.f;
  for (int b = tid; b < 2048; b += 1024) {
    const float4 v = ((const float4*)pslots)[b];
    cox += v.x; cnt += v.y; sim += v.z;
  }
  for (int idx = tid; idx < 2 * NN; idx += 1024) {
    const float4 v = ((const float4*)gsum)[idx];
    const int row = idx & (NN - 1);
    const int gg = row >> 11; // group of permuted row
    const float sg = (gg == 0) ? v.x : (gg == 1) ? v.y : (gg == 2) ? v.z : v.w;
    con += logf(v.x + v.y + v.z + v.w) - logf(sg); // fixed shifts cancel
  }
  for (int m = 1; m < 64; m <<= 1) {
    cox += __shfl_xor(cox, m);
    cnt += __shfl_xor(cnt, m);
    sim += __shfl_xor(sim, m);
    con += __shfl_xor(con, m);
  }
  if (lane == 0) {
    rsum[wv][0] = cox; rsum[wv][1] = cnt; rsum[wv][2] = sim; rsum[wv][3] = con;
  }
  __syncthreads();
  if (tid == 0) {
    float c0 = 0.f, c1 = 0.f, c2 = 0.f, c3 = 0.f;
    for (int k = 0; k < 16; ++k) {
      c0 += rsum[k][0]; c1 += rsum[k][1]; c2 += rsum[k][2]; c3 += rsum[k][3];
    }
    out[0] = -c0 / fmaxf(c1, 1.f) + c2 / (float)NN
             + 0.1f * 0.5f * c3 / (float)NN;
  }
}

extern "C" void kernel_launch(void* const* d_in, const int* in_sizes, int n_in,
                              void* d_out, int out_size, void* d_ws, size_t ws_size,
                              hipStream_t stream) {
  const float* lr = (const float*)d_in[0];
  const float* times = (const float*)d_in[1];
  const int* censor = (const int*)d_in[2];
  const float* wsi = (const float*)d_in[3];
  const float* omic = (const float*)d_in[4];
  float* out = (float*)d_out;

  char* ws = (char*)d_ws;
  float* pslots = (float*)ws;
  float* gsum = (float*)(ws + 32768);
  unsigned char* pw = (unsigned char*)(ws + 294912);
  unsigned char* po = (unsigned char*)(ws + 294912 + 2097152);

  k_rows<<<2048, 256, 0, stream>>>(lr, times, censor, wsi, omic, pw, po, pslots, gsum);
  k_contrast<<<dim3(16, 64, 2), 256, 0, stream>>>(pw, po, gsum);
  k_finale<<<1, 1024, 0, stream>>>(pslots, gsum, out);
}